// Round 1
// baseline (670.164 us; speedup 1.0000x reference)
//
#include <hip/hip_runtime.h>

#define HWN   2304
#define NCI   128
#define NCO   128
#define NBAT  32
#define HT    16
#define ITILE 4
#define JTILE 64
#define NTHR  512
#define NCHUNK (NCI / ITILE)   // 32

// LDS layouts (floats), per buffer:
//   s,b planes: [ITILE][HT][32]  (2048 floats each)
//   w plane:    [ITILE][HT][64]  (4096 floats)
// XOR block-swizzle keeps ds_read_b128 16B-aligned and <=2-way banked.
__device__ __forceinline__ int sb_off(int ii, int l, int col) {
    int blk = ((col >> 2) ^ (l & 7) ^ ii) & 7;
    return ((ii * HT + l) << 5) + (blk << 2) + (col & 3);
}
__device__ __forceinline__ int w_off(int ii, int l, int col) {
    int blk = ((col >> 2) ^ (l & 7) ^ ii) & 15;
    return ((ii * HT + l) << 6) + (blk << 2) + (col & 3);
}

__global__ __launch_bounds__(NTHR, 1)
void centered_lc_main(const float* __restrict__ xg,
                      const float* __restrict__ bg,
                      const float* __restrict__ wg,
                      float* __restrict__ outg,
                      float* __restrict__ mg) {
    __shared__ float lds_s[2][ITILE * HT * 32];
    __shared__ float lds_b[2][ITILE * HT * 32];
    __shared__ float lds_w[2][ITILE * HT * 64];

    const int t   = threadIdx.x;
    const int hc  = blockIdx.x >> 1;      // 0..143  (hw chunk)
    const int jh  = blockIdx.x & 1;       // j-half
    const int hw0 = hc * HT;
    const int j0  = jh * JTILE;

    // compute mapping: lane-of-16 = hw, 32 slots each own an 8b x 8j tile
    const int l    = t & 15;
    const int slot = t >> 4;              // 0..31
    const int b0   = (slot & 3) << 3;     // 0,8,16,24
    const int jq0  = (slot >> 2) << 3;    // 0..56 (wave-uniform)

    // staging mapping: each thread loads float4 along hw
    const int hw4   = (t & 3) << 2;       // 0,4,8,12
    const int arow  = t >> 2;             // 0..127
    const int a_ii  = arow & 3;
    const int a_br  = arow >> 2;          // 0..31
    const int w_jj  = arow & 63;
    const int w_ii0 = arow >> 6;          // 0..1
    const int w_ii1 = w_ii0 + 2;          // 2..3

    const float* xptr  = xg + (a_br * NCI + a_ii) * HWN + hw0 + hw4;
    const float* bptr  = bg + (a_br * NCI + a_ii) * HWN + hw0 + hw4;
    const float* wptr0 = wg + (w_ii0 * NCO + j0 + w_jj) * HWN + hw0 + hw4;
    const float* wptr1 = wg + (w_ii1 * NCO + j0 + w_jj) * HWN + hw0 + hw4;

    float accs[8][8];
    float accb[8][8];
#pragma unroll
    for (int i = 0; i < 8; ++i)
#pragma unroll
        for (int j = 0; j < 8; ++j) { accs[i][j] = 0.f; accb[i][j] = 0.f; }

    auto store_chunk = [&](int buf, float4 vx, float4 vb, float4 vw0, float4 vw1) {
        float4 vs;
        vs.x = vx.x + vb.x; vs.y = vx.y + vb.y; vs.z = vx.z + vb.z; vs.w = vx.w + vb.w;
        lds_s[buf][sb_off(a_ii, hw4 + 0, a_br)] = vs.x;
        lds_s[buf][sb_off(a_ii, hw4 + 1, a_br)] = vs.y;
        lds_s[buf][sb_off(a_ii, hw4 + 2, a_br)] = vs.z;
        lds_s[buf][sb_off(a_ii, hw4 + 3, a_br)] = vs.w;
        lds_b[buf][sb_off(a_ii, hw4 + 0, a_br)] = vb.x;
        lds_b[buf][sb_off(a_ii, hw4 + 1, a_br)] = vb.y;
        lds_b[buf][sb_off(a_ii, hw4 + 2, a_br)] = vb.z;
        lds_b[buf][sb_off(a_ii, hw4 + 3, a_br)] = vb.w;
        lds_w[buf][w_off(w_ii0, hw4 + 0, w_jj)] = vw0.x;
        lds_w[buf][w_off(w_ii0, hw4 + 1, w_jj)] = vw0.y;
        lds_w[buf][w_off(w_ii0, hw4 + 2, w_jj)] = vw0.z;
        lds_w[buf][w_off(w_ii0, hw4 + 3, w_jj)] = vw0.w;
        lds_w[buf][w_off(w_ii1, hw4 + 0, w_jj)] = vw1.x;
        lds_w[buf][w_off(w_ii1, hw4 + 1, w_jj)] = vw1.y;
        lds_w[buf][w_off(w_ii1, hw4 + 2, w_jj)] = vw1.z;
        lds_w[buf][w_off(w_ii1, hw4 + 3, w_jj)] = vw1.w;
    };

    // prologue: load + store chunk 0
    float4 rx  = *(const float4*)(xptr);
    float4 rb  = *(const float4*)(bptr);
    float4 rw0 = *(const float4*)(wptr0);
    float4 rw1 = *(const float4*)(wptr1);
    store_chunk(0, rx, rb, rw0, rw1);

    for (int ic = 0; ic < NCHUNK; ++ic) {
        const int buf = ic & 1;
        if (ic + 1 < NCHUNK) {
            const int s1 = (ic + 1) * (ITILE * HWN);
            const int s2 = (ic + 1) * (ITILE * NCO * HWN);
            rx  = *(const float4*)(xptr + s1);
            rb  = *(const float4*)(bptr + s1);
            rw0 = *(const float4*)(wptr0 + s2);
            rw1 = *(const float4*)(wptr1 + s2);
        }
        __syncthreads();
#pragma unroll
        for (int ii = 0; ii < ITILE; ++ii) {
            const float4 s0 = *(const float4*)&lds_s[buf][sb_off(ii, l, b0)];
            const float4 s1v = *(const float4*)&lds_s[buf][sb_off(ii, l, b0 + 4)];
            const float4 q0 = *(const float4*)&lds_b[buf][sb_off(ii, l, b0)];
            const float4 q1 = *(const float4*)&lds_b[buf][sb_off(ii, l, b0 + 4)];
            const float4 w0 = *(const float4*)&lds_w[buf][w_off(ii, l, jq0)];
            const float4 w1 = *(const float4*)&lds_w[buf][w_off(ii, l, jq0 + 4)];
            const float sv[8] = {s0.x, s0.y, s0.z, s0.w, s1v.x, s1v.y, s1v.z, s1v.w};
            const float qv[8] = {q0.x, q0.y, q0.z, q0.w, q1.x, q1.y, q1.z, q1.w};
            const float wv[8] = {w0.x, w0.y, w0.z, w0.w, w1.x, w1.y, w1.z, w1.w};
#pragma unroll
            for (int bi = 0; bi < 8; ++bi)
#pragma unroll
                for (int ji = 0; ji < 8; ++ji) {
                    accs[bi][ji] = fmaf(sv[bi], wv[ji], accs[bi][ji]);
                    accb[bi][ji] = fmaf(qv[bi], wv[ji], accb[bi][ji]);
                }
        }
        if (ic + 1 < NCHUNK) store_chunk(buf ^ 1, rx, rb, rw0, rw1);
    }

    // epilogue: write s-path result; reduce b-path over the 16 hw lanes -> M
    const int ohw = hw0 + l;
#pragma unroll
    for (int bi = 0; bi < 8; ++bi) {
        const int bglob = b0 + bi;
#pragma unroll
        for (int ji = 0; ji < 8; ++ji) {
            const int jglob = j0 + jq0 + ji;
            outg[(bglob * NCO + jglob) * HWN + ohw] = accs[bi][ji];
            float v = accb[bi][ji];
            v += __shfl_xor(v, 1, 16);
            v += __shfl_xor(v, 2, 16);
            v += __shfl_xor(v, 4, 16);
            v += __shfl_xor(v, 8, 16);
            if (l == 0) atomicAdd(&mg[bglob * NCO + jglob], v);
        }
    }
}

__global__ __launch_bounds__(512, 1)
void centered_lc_fix(float* __restrict__ outg, const float* __restrict__ mg) {
    const int f = blockIdx.x * 512 + threadIdx.x;   // float4 index
    const int bj = f / 576;                         // 576 float4 per (b,j) row
    const float m = mg[bj] * (1.0f / 2304.0f);
    float4* o4 = (float4*)outg;
    float4 o = o4[f];
    o.x -= m; o.y -= m; o.z -= m; o.w -= m;
    o4[f] = o;
}

extern "C" void kernel_launch(void* const* d_in, const int* in_sizes, int n_in,
                              void* d_out, int out_size, void* d_ws, size_t ws_size,
                              hipStream_t stream) {
    const float* x = (const float*)d_in[0];
    const float* b = (const float*)d_in[1];
    const float* w = (const float*)d_in[2];
    float* out = (float*)d_out;
    float* m = (float*)d_ws;

    hipMemsetAsync(m, 0, NBAT * NCO * sizeof(float), stream);
    centered_lc_main<<<dim3(288), dim3(NTHR), 0, stream>>>(x, b, w, out, m);
    centered_lc_fix<<<dim3(4608), dim3(512), 0, stream>>>(out, m);
}

// Round 3
// 380.748 us; speedup vs baseline: 1.7601x; 1.7601x over previous
//
#include <hip/hip_runtime.h>

#define HWN 2304
#define HT  4
#define JT  64
#define NTHR 256

using bf16x8 = __attribute__((ext_vector_type(8))) short;
using f32x4  = __attribute__((ext_vector_type(4))) float;

// LDS: bf16 tiles with 80B rows (32 k-shorts data + 8 pad shorts) -> frag
// ds_read_b128 is 16B-aligned and <=2-way banked. Epilogue reuses as fp32
// out-stage [2048][4].
union Lds {
    struct {
        unsigned short sA[128 * 40];   // [hw*32 + b][40]
        unsigned short bA[128 * 40];   // [hw*32 + b][40]
        unsigned short wB[256 * 40];   // [hw*64 + j][40]
    } st;
    float outst[2048 * 4];             // [b*64+j][hw]
};

__device__ __forceinline__ unsigned short f2bf(float x) {  // RNE fp32->bf16
    unsigned u = __float_as_uint(x);
    u += 0x7FFF + ((u >> 16) & 1);
    return (unsigned short)(u >> 16);
}

__global__ __launch_bounds__(NTHR, 4)
void lc_main(const float* __restrict__ xg, const float* __restrict__ bg,
             const float* __restrict__ wg, float* __restrict__ outg,
             float* __restrict__ mg) {
    __shared__ Lds L;

    // XCD-chunked swizzle: 1152 blocks, 8 XCDs, 144 contiguous units per XCD.
    const int bid  = blockIdx.x;
    const int unit = (bid & 7) * 144 + (bid >> 3);
    const int hc  = unit >> 1;          // 0..575, adjacent on same XCD
    const int jh  = unit & 1;           // j-half sibling adjacent too
    const int hw0 = hc * HT;
    const int j0  = jh * JT;

    const int t   = threadIdx.x;
    const int wv  = t >> 6;
    const int l   = t & 63;
    const int mw  = wv & 1;             // m-tile (b 0..15 / 16..31)
    const int np  = wv >> 1;            // n-pair (2 j-tiles of 16)
    const int l15 = l & 15;
    const int blk = l >> 4;             // k-group 0..3

    const int kq = t & 7;               // k-quad 0..7
    const int bb = t >> 3;              // 0..31 (b-row for sA/bA, j-col for wB)

    f32x4 accS[2][HT];
    f32x4 accB[2];
    const f32x4 zz = {0.f, 0.f, 0.f, 0.f};
#pragma unroll
    for (int n = 0; n < 2; ++n) {
        accB[n] = zz;
#pragma unroll
        for (int h = 0; h < HT; ++h) accS[n][h] = zz;
    }

    for (int kc = 0; kc < 4; ++kc) {
        // ---- load x,b (4 hw x 1 k per load; k-gather across d) ----
        f32x4 rx[4], rb[4];
#pragma unroll
        for (int d = 0; d < 4; ++d) {
            const int row = bb * 128 + kc * 32 + kq * 4 + d;
            rx[d] = *(const f32x4*)(xg + row * HWN + hw0);
            rb[d] = *(const f32x4*)(bg + row * HWN + hw0);
        }
        __syncthreads();   // previous compute done; LDS reusable
#pragma unroll
        for (int h = 0; h < 4; ++h) {
            ushort4 s4 = { f2bf(rx[0][h] + rb[0][h]), f2bf(rx[1][h] + rb[1][h]),
                           f2bf(rx[2][h] + rb[2][h]), f2bf(rx[3][h] + rb[3][h]) };
            ushort4 b4 = { f2bf(rb[0][h]), f2bf(rb[1][h]),
                           f2bf(rb[2][h]), f2bf(rb[3][h]) };
            const int rsb = (h * 32 + bb) * 40 + kq * 4;
            *(ushort4*)&L.st.sA[rsb] = s4;
            *(ushort4*)&L.st.bA[rsb] = b4;
        }
        // ---- load + stage w ----
        f32x4 rw[2][4];
#pragma unroll
        for (int jd = 0; jd < 2; ++jd)
#pragma unroll
        for (int d = 0; d < 4; ++d) {
            const int i = kc * 32 + kq * 4 + d;
            rw[jd][d] = *(const f32x4*)(wg + (i * 128 + j0 + bb + jd * 32) * HWN + hw0);
        }
#pragma unroll
        for (int jd = 0; jd < 2; ++jd)
#pragma unroll
        for (int h = 0; h < 4; ++h) {
            ushort4 w4 = { f2bf(rw[jd][0][h]), f2bf(rw[jd][1][h]),
                           f2bf(rw[jd][2][h]), f2bf(rw[jd][3][h]) };
            *(ushort4*)&L.st.wB[(h * 64 + bb + jd * 32) * 40 + kq * 4] = w4;
        }
        __syncthreads();
        // ---- compute: per hw, A(row=b) x B(col=j), k consistent for A and B ----
#pragma unroll
        for (int h = 0; h < 4; ++h) {
            bf16x8 aS = *(const bf16x8*)&L.st.sA[(h * 32 + mw * 16 + l15) * 40 + blk * 8];
            bf16x8 aB = *(const bf16x8*)&L.st.bA[(h * 32 + mw * 16 + l15) * 40 + blk * 8];
#pragma unroll
            for (int n = 0; n < 2; ++n) {
                bf16x8 wf = *(const bf16x8*)&L.st.wB[(h * 64 + (np * 2 + n) * 16 + l15) * 40 + blk * 8];
                accS[n][h] = __builtin_amdgcn_mfma_f32_16x16x32_bf16(aS, wf, accS[n][h], 0, 0, 0);
                accB[n]    = __builtin_amdgcn_mfma_f32_16x16x32_bf16(aB, wf, accB[n],    0, 0, 0);
            }
        }
    }

    __syncthreads();   // frag reads done; reuse LDS as out-stage
    // C/D layout (verified): col = lane&15, row = 4*(lane>>4) + reg
#pragma unroll
    for (int n = 0; n < 2; ++n) {
        const int jc = (np * 2 + n) * 16 + l15;
#pragma unroll
        for (int r = 0; r < 4; ++r) {
            const int p = (mw * 16 + blk * 4 + r) * 64 + jc;
#pragma unroll
            for (int h = 0; h < 4; ++h)
                L.outst[p * 4 + h] = accS[n][h][r];
        }
    }
    __syncthreads();
#pragma unroll
    for (int i = 0; i < 8; ++i) {
        const int p = i * 256 + t;
        const float4 v = *(const float4*)&L.outst[p * 4];
        const int br = p >> 6, jl = p & 63;
        *(float4*)(outg + (br * 128 + j0 + jl) * HWN + hw0) = v;
    }
#pragma unroll
    for (int n = 0; n < 2; ++n) {
        const int jc = j0 + (np * 2 + n) * 16 + l15;
#pragma unroll
        for (int r = 0; r < 4; ++r)
            atomicAdd(&mg[(mw * 16 + blk * 4 + r) * 128 + jc], accB[n][r]);
    }
}

__global__ __launch_bounds__(576)
void lc_fix(float* __restrict__ outg, const float* __restrict__ mg) {
    const int bj = blockIdx.x;                 // (b*128+j) row
    const float m = mg[bj] * (1.0f / 2304.0f);
    float4* p = (float4*)(outg + bj * HWN) + threadIdx.x;
    float4 v = *p;
    v.x -= m; v.y -= m; v.z -= m; v.w -= m;
    *p = v;
}

extern "C" void kernel_launch(void* const* d_in, const int* in_sizes, int n_in,
                              void* d_out, int out_size, void* d_ws, size_t ws_size,
                              hipStream_t stream) {
    const float* x = (const float*)d_in[0];
    const float* b = (const float*)d_in[1];
    const float* w = (const float*)d_in[2];
    float* out = (float*)d_out;
    float* m   = (float*)d_ws;

    hipMemsetAsync(m, 0, 32 * 128 * sizeof(float), stream);
    lc_main<<<1152, NTHR, 0, stream>>>(x, b, w, out, m);
    lc_fix<<<4096, 576, 0, stream>>>(out, m);
}